// Round 13
// baseline (762.546 us; speedup 1.0000x reference)
//
#include <hip/hip_runtime.h>
#include <math.h>

#if __has_builtin(__builtin_amdgcn_exp2f)
#define EXP2(x) __builtin_amdgcn_exp2f(x)
#else
#define EXP2(x) exp2f(x)
#endif

#define ALPHA_LRELU 0.2f
#define LOG2E 1.4426950408889634f
#define ESHIFT 6.0f
#define BIGM 1024.0f  // bit=0 -> exp2 arg < -1000 -> p = 0

constexpr int Bc = 2, Nn = 2048, Ff = 256, Hh = 8, Oo = 32;
constexpr int NBLK = 1024;

typedef _Float16 f16;
typedef f16 f16x8 __attribute__((ext_vector_type(8)));
typedef f16 f16x4 __attribute__((ext_vector_type(4)));
typedef float f32x4 __attribute__((ext_vector_type(4)));
typedef unsigned long long u64;
typedef unsigned u32;

// ---------------------------------------------------------------------------
// init: zero s-buffers and grid-barrier counters (kernel boundary makes these
// visible to the mega kernel). Idempotent per call.
// ---------------------------------------------------------------------------
__global__ __launch_bounds__(256) void init_kernel(float* __restrict__ sbuf,
                                                   u32* __restrict__ bar) {
    int g = blockIdx.x * 256 + threadIdx.x;
    if (g < 544) bar[g] = 0;
    if (g < 221184) sbuf[g] = 0.f;  // 3 * (2*SH + 2*SO)
}

// ---------------------------------------------------------------------------
// Two-level grid barrier: 16 group counters (128B apart) -> 1 root.
// Monotonic counts (no reset). Agent-scope atomics + threadfence for
// cross-XCD visibility. All NBLK blocks co-resident (launch_bounds(256,4)).
// ---------------------------------------------------------------------------
__device__ __forceinline__ void gridbar(u32* bar, int ph) {
    __syncthreads();
    if (threadIdx.x == 0) {
        __threadfence();  // release my block's writes device-wide
        u32* lv1 = bar + 32 + (blockIdx.x & 15) * 32;
        u32 old = __hip_atomic_fetch_add(lv1, 1u, __ATOMIC_RELAXED,
                                         __HIP_MEMORY_SCOPE_AGENT);
        if (old == (u32)(ph * 64 + 63))  // last of this group's 64 blocks
            __hip_atomic_fetch_add(bar, 1u, __ATOMIC_RELAXED,
                                   __HIP_MEMORY_SCOPE_AGENT);
        while (__hip_atomic_load(bar, __ATOMIC_RELAXED,
                                 __HIP_MEMORY_SCOPE_AGENT) <
               (u32)(ph * 16 + 16))
            __builtin_amdgcn_s_sleep(2);
        __threadfence();  // acquire: invalidate stale caches
    }
    __syncthreads();
}

// ---------------------------------------------------------------------------
// GEMM phase (R12 gemm_wave body): wave = 16 rows x 16 cols, frag-packed
// operands, epilogue writes WhFrag + s1/s2 atomics.
// ---------------------------------------------------------------------------
__device__ __forceinline__ void gemm_phase(
    const f16* __restrict__ Af, const f16* __restrict__ WTF,
    const float* __restrict__ pa, f16* __restrict__ WhFrag,
    float* __restrict__ s1, float* __restrict__ s2,
    int G, int Ofull, int oshift, int xb, int yb) {
    int t = threadIdx.x;
    int w = t >> 6, lane = t & 63;
    int am = lane & 15, aq = lane >> 4;
    int mt = xb * 4 + w;
    int colb = yb * 16;

    const f16* ap = Af + (size_t)(mt * 8) * 512 + lane * 8;
    const f16* bp = WTF + (size_t)((colb >> 4) * 8) * 512 + lane * 8;

    f32x4 acc = {0.f, 0.f, 0.f, 0.f};
    f16x8 a0 = *(const f16x8*)ap;
    f16x8 b0 = *(const f16x8*)bp;
#pragma unroll
    for (int c = 0; c < 8; ++c) {
        int cn = (c + 1 < 8) ? c + 1 : 0;
        f16x8 an = *(const f16x8*)(ap + cn * 512);
        f16x8 bn = *(const f16x8*)(bp + cn * 512);
        acc = __builtin_amdgcn_mfma_f32_16x16x32_f16(a0, b0, acc, 0, 0, 0);
        a0 = an; b0 = bn;
    }

    int m0 = mt * 16;
    int b = m0 >> 11;
    int nn0 = (m0 & 2047) + aq * 4;
    int cO = (m0 & 2047) >> 5;
    int aq_p = ((mt & 1) << 1) | (aq >> 1);
    int i0p = (aq & 1) << 2;
    int g = colb >> oshift;
    size_t bg = (size_t)b * G + g;
    int cg = (colb & (Ofull - 1)) >> 4;

    f16x4 c4;
#pragma unroll
    for (int e = 0; e < 4; ++e) c4[e] = (f16)acc[e];
    *(f16x4*)&WhFrag[(((bg * (Ofull >> 4) + cg) * 64 + cO) * 512) +
                     (aq_p * 16 + am) * 8 + i0p] = c4;

    int o0 = (colb & (Ofull - 1)) + am;
    const float* a1p = pa + 2 * (size_t)g * Ofull;
    float a10 = a1p[o0];
    float a20 = a1p[Ofull + o0];
#pragma unroll
    for (int e = 0; e < 4; ++e) {
        float p1 = acc[e] * a10;
        float p2 = acc[e] * a20;
#pragma unroll
        for (int s = 1; s < 16; s <<= 1) {
            p1 += __shfl_xor(p1, s);
            p2 += __shfl_xor(p2, s);
        }
        if (am == 0) {
            size_t sidx = bg * Nn + nn0 + e;
            atomicAdd(&s1[sidx], p1);
            atomicAdd(&s2[sidx], p2);
        }
    }
}

// ---------------------------------------------------------------------------
// Attention phase (R12 attn_kernel body): j-split x2 + prefetch-2,
// e-in-registers, coalesced frag loads, fused Af epilogue.
// ---------------------------------------------------------------------------
template <bool OUT, bool FINAL>
__device__ __forceinline__ void attn_phase(
    const f16* __restrict__ WhFrag, const float* __restrict__ s1,
    const float* __restrict__ s2, const u32* __restrict__ maskT,
    float* __restrict__ dst, f16* __restrict__ AfOut,
    int xb, int yb, int bz,
    float (&Ls)[4][64], float (&As)[4][64][8], f16 (&T)[2][640]) {
    constexpr float C0 = -ESHIFT * LOG2E - BIGM;
    constexpr int NCG = OUT ? 16 : 2;
    constexpr int TSTR = 40;

    int t = threadIdx.x;
    int w = t >> 6, lane = t & 63;
    int am = lane & 15, aq = lane >> 4;
    int wr = w & 1;   // row tile within block
    int wh = w >> 1;  // j half
    int i0 = xb * 32 + wr * 16;
    int b = OUT ? bz : (bz >> 3);
    int cg0 = OUT ? yb * 2 : 0;
    int dstcol = OUT ? cg0 * 16 : (bz & 7) * Oo;

    const f16* bp0 = WhFrag + ((size_t)bz * NCG + cg0) * 64 * 512 + lane * 8;
    const f16* bp1 = bp0 + 64 * 512;
    const float* s2p = s2 + (size_t)bz * Nn + aq * 8;
    float s1v = s1[(size_t)bz * Nn + i0 + am];
    const u32* mtp = maskT + (size_t)b * 64 * 2048 + i0 + am;

    f32x4 acc0 = {0.f, 0.f, 0.f, 0.f}, acc1 = acc0;
    float lacc = 0.f;

    int cbeg = wh * 32, cend = cbeg + 32;

    f16x8 xb0, xb1, yb0, yb1;
    f32x4 xv0, xv1, yv0, yv1;
    u32 xm, ym;
    auto ld = [&](int c, f16x8& b0, f16x8& b1, f32x4& v0, f32x4& v1, u32& m) {
        b0 = *(const f16x8*)(bp0 + c * 512);
        b1 = *(const f16x8*)(bp1 + c * 512);
        v0 = *(const f32x4*)(s2p + c * 32);
        v1 = *(const f32x4*)(s2p + c * 32 + 4);
        m = mtp[c * 2048];
    };
    auto comp = [&](f16x8 b0, f16x8 b1, f32x4 v0, f32x4 v1, u32 m) {
        u32 bits = (m >> (aq * 8)) & 0xffu;
        f16x8 af;
#pragma unroll
        for (int k = 0; k < 8; ++k) {
            float xv = s1v + (k < 4 ? v0[k] : v1[k - 4]);
            float lr = fmaxf(xv, ALPHA_LRELU * xv);
            float bitf = (float)((bits >> k) & 1u);
            float p = EXP2(fmaf(bitf, BIGM, fmaf(lr, LOG2E, C0)));
            lacc += p;
            af[k] = (f16)p;
        }
        acc0 = __builtin_amdgcn_mfma_f32_16x16x32_f16(af, b0, acc0, 0, 0, 0);
        acc1 = __builtin_amdgcn_mfma_f32_16x16x32_f16(af, b1, acc1, 0, 0, 0);
    };

    ld(cbeg, xb0, xb1, xv0, xv1, xm);
    ld(cbeg + 1, yb0, yb1, yv0, yv1, ym);
    for (int c = cbeg; c < cend; c += 2) {
        comp(xb0, xb1, xv0, xv1, xm);
        ld(c + 2 < cend ? c + 2 : cbeg, xb0, xb1, xv0, xv1, xm);
        comp(yb0, yb1, yv0, yv1, ym);
        ld(c + 3 < cend ? c + 3 : cbeg, yb0, yb1, yv0, yv1, ym);
    }

    // intra-wave l: sum over aq groups -> lane holds l_half[am]
    lacc += __shfl_xor(lacc, 16);
    lacc += __shfl_xor(lacc, 32);

    // cross-wave combine of the two j-halves
    Ls[w][lane] = lacc;
#pragma unroll
    for (int e = 0; e < 4; ++e) {
        As[w][lane][e] = acc0[e];
        As[w][lane][4 + e] = acc1[e];
    }
    __syncthreads();

    if (wh == 0) {
        float lt = Ls[w][lane] + Ls[w + 2][lane];
        f32x4 a0, a1;
#pragma unroll
        for (int e = 0; e < 4; ++e) {
            a0[e] = As[w][lane][e] + As[w + 2][lane][e];
            a1[e] = As[w][lane][4 + e] + As[w + 2][lane][4 + e];
        }
        f16* Tw = T[wr];
#pragma unroll
        for (int e = 0; e < 4; ++e) {
            int r = aq * 4 + e;             // C/D: col=am, row=aq*4+e
            float li = __shfl(lt, r);       // lane r holds l[row r]
            float v0 = a0[e] / li, v1 = a1[e] / li;
            v0 = v0 > 0.f ? v0 : __expf(v0) - 1.f;
            v1 = v1 > 0.f ? v1 : __expf(v1) - 1.f;
            if (OUT) {
                v0 = v0 > 0.f ? v0 : __expf(v0) - 1.f;
                v1 = v1 > 0.f ? v1 : __expf(v1) - 1.f;
            }
            if (FINAL) {
                size_t base = ((size_t)b * Nn + i0 + r) * Ff + dstcol;
                dst[base + am] = v0;
                dst[base + 16 + am] = v1;
            } else {
                Tw[r * TSTR + am] = (f16)v0;
                Tw[r * TSTR + 16 + am] = (f16)v1;
            }
        }
        if (!FINAL) {
            // in-wave read-back in A-frag order (no barrier: same wave's data)
            f16x8 o = *(const f16x8*)&Tw[am * TSTR + aq * 8];
            int mt = (b * Nn + i0) >> 4;   // GLOBAL row tile
            int c = dstcol >> 5;
            *(f16x8*)&AfOut[(size_t)(mt * 8 + c) * 512 + lane * 8] = o;
        }
    }
}

// ---------------------------------------------------------------------------
// Mega kernel: all 13 phases, one launch. 1024 blocks, all co-resident
// (launch_bounds(256,4) => <=128 VGPR => 4 blocks/CU).
// ---------------------------------------------------------------------------
__global__ __launch_bounds__(256, 4) void mega_kernel(
    const int* __restrict__ adj, const float* __restrict__ x,
    const float* __restrict__ W_heads, const float* __restrict__ a_heads,
    const float* __restrict__ W_out, const float* __restrict__ a_out,
    float* __restrict__ out, f16* __restrict__ Af_a, f16* __restrict__ Af_b,
    f16* __restrict__ WhFrag, u32* __restrict__ maskT, f16* __restrict__ WTF,
    float* __restrict__ sbuf, u32* __restrict__ bar) {
    __shared__ float Ls[4][64];
    __shared__ float As[4][64][8];
    __shared__ f16 T[2][640];

    const int B = blockIdx.x;
    const int t = threadIdx.x;
    int ph = 0;

    // ---- P0: prep (partitioned by block range) ----
    if (B < 768) {
        // adj -> transposed bitmask
        for (int idx = B * 256 + t; idx < Bc * Nn * Nn; idx += 768 * 256) {
            u64 bl = __ballot(adj[idx] != 0);
            int lane = t & 63;
            int i = (idx >> 11) & 2047;
            int b = idx >> 22;
            int c32 = ((idx & 2047) & ~63) >> 5;
            if (lane == 0)
                maskT[((size_t)b * 64 + c32) * 2048 + i] = (u32)bl;
            else if (lane == 1)
                maskT[((size_t)b * 64 + c32 + 1) * 2048 + i] = (u32)(bl >> 32);
        }
    } else if (B < 896) {
        // apack: fp32 x -> A-frag f16 (2048 slot-waves)
        int w = t >> 6, lane = t & 63;
        int am = lane & 15, aq = lane >> 4;
#pragma unroll
        for (int it = 0; it < 4; ++it) {
            int slot = (B - 768) * 4 + w + it * 512;
            int mt = slot >> 3, c = slot & 7;
            const float* ap = x + ((size_t)mt * 16 + am) * Ff + c * 32 + aq * 8;
            f32x4 v0 = *(const f32x4*)ap;
            f32x4 v1 = *(const f32x4*)(ap + 4);
            f16x8 o;
#pragma unroll
            for (int i = 0; i < 4; ++i) { o[i] = (f16)v0[i]; o[4 + i] = (f16)v1[i]; }
            *(f16x8*)&Af_a[(size_t)slot * 512 + lane * 8] = o;
        }
    } else {
        // weights -> B-frag f16 (384 block-units)
#pragma unroll
        for (int it = 0; it < 3; ++it) {
            int unit = (B - 896) * 3 + it;  // 0..383
            int y = unit >> 6, bx = unit & 63;
            int ll = y >> 1, st = y & 1;
            int col = bx * 4 + (t >> 6);
            int k0 = (t & 63) * 4;
            const float* src;
            int stride;
            if (st == 0) {
                src = W_heads + (((size_t)ll * Hh + (col >> 5)) * Ff) * Oo + (col & 31);
                stride = Oo;
            } else {
                src = W_out + (size_t)ll * Ff * Ff + col;
                stride = Ff;
            }
            f16x4 v;
#pragma unroll
            for (int i = 0; i < 4; ++i) v[i] = (f16)src[(size_t)(k0 + i) * stride];
            int cg = col >> 4, am = col & 15;
            int c = k0 >> 5, aq = (k0 >> 3) & 3, i0 = k0 & 7;
            *(f16x4*)&WTF[(((size_t)y * 16 + cg) * 8 + c) * 512 +
                          (aq * 16 + am) * 8 + i0] = v;
        }
    }
    gridbar(bar, ph++);

    const size_t SH = (size_t)Bc * Hh * Nn;  // 32768
    const size_t SO = (size_t)Bc * Nn;       // 4096
    const size_t SL = 2 * SH + 2 * SO;

    for (int l = 0; l < 3; ++l) {
        float* s1h = sbuf + l * SL;
        float* s2h = s1h + SH;
        float* s1o = s2h + SH;
        float* s2o = s1o + SO;

        // ---- head GAT: G=8, O=32 ----
        gemm_phase(Af_a, WTF + (size_t)(2 * l) * Ff * Ff,
                   a_heads + (size_t)l * Hh * 2 * Oo, WhFrag, s1h, s2h,
                   Hh, Oo, 5, B & 63, B >> 6);
        gridbar(bar, ph++);
        attn_phase<false, false>(WhFrag, s1h, s2h, maskT, nullptr, Af_b,
                                 B & 63, 0, B >> 6, Ls, As, T);
        gridbar(bar, ph++);

        // ---- out GAT: G=1, O=F=256 ----
        gemm_phase(Af_b, WTF + (size_t)(2 * l + 1) * Ff * Ff,
                   a_out + (size_t)l * 2 * Ff, WhFrag, s1o, s2o,
                   1, Ff, 8, B & 63, B >> 6);
        gridbar(bar, ph++);
        if (l == 2) {
            attn_phase<true, true>(WhFrag, s1o, s2o, maskT, out, nullptr,
                                   B & 63, (B >> 6) & 7, B >> 9, Ls, As, T);
        } else {
            attn_phase<true, false>(WhFrag, s1o, s2o, maskT, nullptr, Af_a,
                                    B & 63, (B >> 6) & 7, B >> 9, Ls, As, T);
            gridbar(bar, ph++);
        }
    }
}

// ---------------------------------------------------------------------------
extern "C" void kernel_launch(void* const* d_in, const int* in_sizes, int n_in,
                              void* d_out, int out_size, void* d_ws, size_t ws_size,
                              hipStream_t stream) {
    const float* x = (const float*)d_in[0];
    const int* adj = (const int*)d_in[1];
    const float* W_heads = (const float*)d_in[2];
    const float* a_heads = (const float*)d_in[3];
    const float* W_out = (const float*)d_in[4];
    const float* a_out = (const float*)d_in[5];
    float* out = (float*)d_out;

    float* ws = (float*)d_ws;
    const size_t M = (size_t)Bc * Nn * Ff;        // 1,048,576
    f16* Af_a = (f16*)ws;                         // M f16
    f16* Af_b = (f16*)(ws + M / 2);               // M f16
    f16* WhFrag = (f16*)(ws + M);                 // M f16
    u32* maskT = (u32*)(ws + 3 * M / 2);          // 1 MB
    f16* WTF = (f16*)(ws + 3 * M / 2 + M / 4);    // 6*F*F f16 = 196608 floats
    float* sbuf = ws + 3 * M / 2 + M / 4 + 196608;  // 221184 floats
    u32* bar = (u32*)(sbuf + 221184);             // 544 u32

    init_kernel<<<NBLK, 256, 0, stream>>>(sbuf, bar);
    mega_kernel<<<NBLK, 256, 0, stream>>>(
        adj, x, W_heads, a_heads, W_out, a_out, out,
        Af_a, Af_b, WhFrag, maskT, WTF, sbuf, bar);
}

// Round 14
// 289.721 us; speedup vs baseline: 2.6320x; 2.6320x over previous
//
#include <hip/hip_runtime.h>
#include <math.h>

#if __has_builtin(__builtin_amdgcn_exp2f)
#define EXP2(x) __builtin_amdgcn_exp2f(x)
#else
#define EXP2(x) exp2f(x)
#endif

#define ALPHA_LRELU 0.2f
#define LOG2E 1.4426950408889634f
#define ESHIFT 6.0f
#define BIGM 1024.0f  // bit=0 -> exp2 arg < -1000 -> p = 0

constexpr int Bc = 2, Nn = 2048, Ff = 256, Hh = 8, Oo = 32;

typedef _Float16 f16;
typedef f16 f16x8 __attribute__((ext_vector_type(8)));
typedef f16 f16x4 __attribute__((ext_vector_type(4)));
typedef float f32x4 __attribute__((ext_vector_type(4)));
typedef unsigned long long u64;
typedef unsigned u32;

// ---------------------------------------------------------------------------
// Fused prep (one launch, block-range partitioned; bodies = R13's verified P0):
//   all blocks: zero s-buffers;  B<768: adj->maskT;  768..895: apack x;
//   896..1023: weights -> B-frag WTF.
// ---------------------------------------------------------------------------
__global__ __launch_bounds__(256) void prep_kernel(
    const int* __restrict__ adj, const float* __restrict__ x,
    const float* __restrict__ W_heads, const float* __restrict__ W_out,
    u32* __restrict__ maskT, f16* __restrict__ Af, f16* __restrict__ WTF,
    float* __restrict__ sbuf) {
    const int B = blockIdx.x;
    const int t = threadIdx.x;
    int g = B * 256 + t;
    if (g < 221184) sbuf[g] = 0.f;  // 3 * (2*SH + 2*SO)

    if (B < 768) {
        for (int idx = g; idx < Bc * Nn * Nn; idx += 768 * 256) {
            u64 bl = __ballot(adj[idx] != 0);
            int lane = t & 63;
            int i = (idx >> 11) & 2047;
            int b = idx >> 22;
            int c32 = ((idx & 2047) & ~63) >> 5;
            if (lane == 0)
                maskT[((size_t)b * 64 + c32) * 2048 + i] = (u32)bl;
            else if (lane == 1)
                maskT[((size_t)b * 64 + c32 + 1) * 2048 + i] = (u32)(bl >> 32);
        }
    } else if (B < 896) {
        int w = t >> 6, lane = t & 63;
        int am = lane & 15, aq = lane >> 4;
#pragma unroll
        for (int it = 0; it < 4; ++it) {
            int slot = (B - 768) * 4 + w + it * 512;
            int mt = slot >> 3, c = slot & 7;
            const float* ap = x + ((size_t)mt * 16 + am) * Ff + c * 32 + aq * 8;
            f32x4 v0 = *(const f32x4*)ap;
            f32x4 v1 = *(const f32x4*)(ap + 4);
            f16x8 o;
#pragma unroll
            for (int i = 0; i < 4; ++i) { o[i] = (f16)v0[i]; o[4 + i] = (f16)v1[i]; }
            *(f16x8*)&Af[(size_t)slot * 512 + lane * 8] = o;
        }
    } else {
#pragma unroll
        for (int it = 0; it < 3; ++it) {
            int unit = (B - 896) * 3 + it;  // 0..383
            int y = unit >> 6, bx = unit & 63;
            int ll = y >> 1, st = y & 1;
            int col = bx * 4 + (t >> 6);
            int k0 = (t & 63) * 4;
            const float* src;
            int stride;
            if (st == 0) {
                src = W_heads + (((size_t)ll * Hh + (col >> 5)) * Ff) * Oo + (col & 31);
                stride = Oo;
            } else {
                src = W_out + (size_t)ll * Ff * Ff + col;
                stride = Ff;
            }
            f16x4 v;
#pragma unroll
            for (int i = 0; i < 4; ++i) v[i] = (f16)src[(size_t)(k0 + i) * stride];
            int cg = col >> 4, am = col & 15;
            int c = k0 >> 5, aq = (k0 >> 3) & 3, i0 = k0 & 7;
            *(f16x4*)&WTF[(((size_t)y * 16 + cg) * 8 + c) * 512 +
                          (aq * 16 + am) * 8 + i0] = v;
        }
    }
}

// ---------------------------------------------------------------------------
// Frag GEMM (unchanged from R12): wave = 16 rows x 16 cols, frag-packed
// operands (1KB/wave coalesced loads). Epilogue: WhFrag + s1/s2 atomics.
// ---------------------------------------------------------------------------
__global__ __launch_bounds__(256) void gemm_wave(
    const f16* __restrict__ Af, const f16* __restrict__ WTF,
    const float* __restrict__ pa, f16* __restrict__ WhFrag,
    float* __restrict__ s1, float* __restrict__ s2,
    int G, int Ofull, int oshift) {
    int t = threadIdx.x;
    int w = t >> 6, lane = t & 63;
    int am = lane & 15, aq = lane >> 4;
    int mt = blockIdx.x * 4 + w;
    int colb = blockIdx.y * 16;

    const f16* ap = Af + (size_t)(mt * 8) * 512 + lane * 8;
    const f16* bp = WTF + (size_t)((colb >> 4) * 8) * 512 + lane * 8;

    f32x4 acc = {0.f, 0.f, 0.f, 0.f};
    f16x8 a0 = *(const f16x8*)ap;
    f16x8 b0 = *(const f16x8*)bp;
#pragma unroll
    for (int c = 0; c < 8; ++c) {
        int cn = (c + 1 < 8) ? c + 1 : 0;
        f16x8 an = *(const f16x8*)(ap + cn * 512);
        f16x8 bn = *(const f16x8*)(bp + cn * 512);
        acc = __builtin_amdgcn_mfma_f32_16x16x32_f16(a0, b0, acc, 0, 0, 0);
        a0 = an; b0 = bn;
    }

    int m0 = mt * 16;
    int b = m0 >> 11;
    int nn0 = (m0 & 2047) + aq * 4;
    int cO = (m0 & 2047) >> 5;
    int aq_p = ((mt & 1) << 1) | (aq >> 1);
    int i0p = (aq & 1) << 2;
    int g = colb >> oshift;
    size_t bg = (size_t)b * G + g;
    int cg = (colb & (Ofull - 1)) >> 4;

    f16x4 c4;
#pragma unroll
    for (int e = 0; e < 4; ++e) c4[e] = (f16)acc[e];
    *(f16x4*)&WhFrag[(((bg * (Ofull >> 4) + cg) * 64 + cO) * 512) +
                     (aq_p * 16 + am) * 8 + i0p] = c4;

    int o0 = (colb & (Ofull - 1)) + am;
    const float* a1p = pa + 2 * (size_t)g * Ofull;
    float a10 = a1p[o0];
    float a20 = a1p[Ofull + o0];
#pragma unroll
    for (int e = 0; e < 4; ++e) {
        float p1 = acc[e] * a10;
        float p2 = acc[e] * a20;
#pragma unroll
        for (int s = 1; s < 16; s <<= 1) {
            p1 += __shfl_xor(p1, s);
            p2 += __shfl_xor(p2, s);
        }
        if (am == 0) {
            size_t sidx = bg * Nn + nn0 + e;
            atomicAdd(&s1[sidx], p1);
            atomicAdd(&s2[sidx], p2);
        }
    }
}

// ---------------------------------------------------------------------------
// Attention: wave = 2 ROW-TILES (32 rows) x 32 cols, j-split x4 (16 chunks
// per wave). B-frags loaded once serve BOTH row tiles -> L1 bytes per logit
// halved vs R12 (the measured TA-saturation bottleneck). Prefetch-2.
// End: one barrier, 4-way LDS combine, waves 0/1 do the two tile epilogues
// (verbatim R12 numerics + fused Af writeback).
// Head grid (64,1,16); Out grid (64,8,2) -> 1024 blocks, 16 waves/CU.
// ---------------------------------------------------------------------------
template <bool OUT, bool FINAL>
__global__ __launch_bounds__(256) void attn_kernel(
    const f16* __restrict__ WhFrag, const float* __restrict__ s1,
    const float* __restrict__ s2, const u32* __restrict__ maskT,
    float* __restrict__ dst, f16* __restrict__ AfOut) {
    constexpr float C0 = -ESHIFT * LOG2E - BIGM;
    constexpr int NCG = OUT ? 16 : 2;
    constexpr int TSTR = 40;
    __shared__ float Ls[4][2][64];
    __shared__ float As[4][64][16];
    __shared__ f16 T[2][16 * TSTR];

    int t = threadIdx.x;
    int w = t >> 6, lane = t & 63;
    int am = lane & 15, aq = lane >> 4;
    int i0 = blockIdx.x * 32;
    int bz = blockIdx.z;
    int b = OUT ? bz : (bz >> 3);
    int cg0 = OUT ? blockIdx.y * 2 : 0;
    int dstcol = OUT ? cg0 * 16 : (bz & 7) * Oo;

    const f16* bp0 = WhFrag + ((size_t)bz * NCG + cg0) * 64 * 512 + lane * 8;
    const f16* bp1 = bp0 + 64 * 512;
    const float* s2p = s2 + (size_t)bz * Nn + aq * 8;
    float s1v0 = s1[(size_t)bz * Nn + i0 + am];
    float s1v1 = s1[(size_t)bz * Nn + i0 + 16 + am];
    const u32* mtp0 = maskT + (size_t)b * 64 * 2048 + i0 + am;
    const u32* mtp1 = mtp0 + 16;

    f32x4 acc00 = {0.f, 0.f, 0.f, 0.f}, acc01 = acc00, acc10 = acc00, acc11 = acc00;
    float lacc0 = 0.f, lacc1 = 0.f;

    int cbeg = w * 16, cend = cbeg + 16;  // this wave's j-slice (16 chunks)

    f16x8 xb0, xb1, yb0, yb1;
    f32x4 xv0, xv1, yv0, yv1;
    u32 xm0, xm1, ym0, ym1;
    auto ld = [&](int c, f16x8& b0, f16x8& b1, f32x4& v0, f32x4& v1,
                  u32& m0, u32& m1) {
        b0 = *(const f16x8*)(bp0 + c * 512);
        b1 = *(const f16x8*)(bp1 + c * 512);
        v0 = *(const f32x4*)(s2p + c * 32);
        v1 = *(const f32x4*)(s2p + c * 32 + 4);
        m0 = mtp0[c * 2048];
        m1 = mtp1[c * 2048];
    };
    auto comp = [&](f16x8 b0, f16x8 b1, f32x4 v0, f32x4 v1, u32 m0, u32 m1) {
        u32 bits0 = (m0 >> (aq * 8)) & 0xffu;
        u32 bits1 = (m1 >> (aq * 8)) & 0xffu;
        f16x8 af0, af1;
#pragma unroll
        for (int k = 0; k < 8; ++k) {
            float sv = (k < 4 ? v0[k] : v1[k - 4]);
            float x0 = s1v0 + sv;
            float x1 = s1v1 + sv;
            float lr0 = fmaxf(x0, ALPHA_LRELU * x0);
            float lr1 = fmaxf(x1, ALPHA_LRELU * x1);
            float bf0 = (float)((bits0 >> k) & 1u);
            float bf1 = (float)((bits1 >> k) & 1u);
            float p0 = EXP2(fmaf(bf0, BIGM, fmaf(lr0, LOG2E, C0)));
            float p1 = EXP2(fmaf(bf1, BIGM, fmaf(lr1, LOG2E, C0)));
            lacc0 += p0;
            lacc1 += p1;
            af0[k] = (f16)p0;
            af1[k] = (f16)p1;
        }
        acc00 = __builtin_amdgcn_mfma_f32_16x16x32_f16(af0, b0, acc00, 0, 0, 0);
        acc01 = __builtin_amdgcn_mfma_f32_16x16x32_f16(af0, b1, acc01, 0, 0, 0);
        acc10 = __builtin_amdgcn_mfma_f32_16x16x32_f16(af1, b0, acc10, 0, 0, 0);
        acc11 = __builtin_amdgcn_mfma_f32_16x16x32_f16(af1, b1, acc11, 0, 0, 0);
    };

    ld(cbeg, xb0, xb1, xv0, xv1, xm0, xm1);
    ld(cbeg + 1, yb0, yb1, yv0, yv1, ym0, ym1);
    for (int c = cbeg; c < cend; c += 2) {
        comp(xb0, xb1, xv0, xv1, xm0, xm1);
        ld(c + 2 < cend ? c + 2 : cbeg, xb0, xb1, xv0, xv1, xm0, xm1);
        comp(yb0, yb1, yv0, yv1, ym0, ym1);
        ld(c + 3 < cend ? c + 3 : cbeg, yb0, yb1, yv0, yv1, ym0, ym1);
    }

    // intra-wave l: sum over aq groups -> lane holds l_slice[am] per tile
    lacc0 += __shfl_xor(lacc0, 16);
    lacc0 += __shfl_xor(lacc0, 32);
    lacc1 += __shfl_xor(lacc1, 16);
    lacc1 += __shfl_xor(lacc1, 32);

    Ls[w][0][lane] = lacc0;
    Ls[w][1][lane] = lacc1;
#pragma unroll
    for (int e = 0; e < 4; ++e) {
        As[w][lane][e] = acc00[e];
        As[w][lane][4 + e] = acc01[e];
        As[w][lane][8 + e] = acc10[e];
        As[w][lane][12 + e] = acc11[e];
    }
    __syncthreads();

    if (w < 2) {  // wave w finishes row tile w
        float lt = Ls[0][w][lane] + Ls[1][w][lane] + Ls[2][w][lane] + Ls[3][w][lane];
        f32x4 a0, a1;
#pragma unroll
        for (int e = 0; e < 4; ++e) {
            a0[e] = As[0][lane][w * 8 + e] + As[1][lane][w * 8 + e] +
                    As[2][lane][w * 8 + e] + As[3][lane][w * 8 + e];
            a1[e] = As[0][lane][w * 8 + 4 + e] + As[1][lane][w * 8 + 4 + e] +
                    As[2][lane][w * 8 + 4 + e] + As[3][lane][w * 8 + 4 + e];
        }
        f16* Tw = T[w];
#pragma unroll
        for (int e = 0; e < 4; ++e) {
            int r = aq * 4 + e;             // C/D: col=am, row=aq*4+e
            float li = __shfl(lt, r);       // lane r holds l[row r]
            float v0 = a0[e] / li, v1 = a1[e] / li;
            v0 = v0 > 0.f ? v0 : __expf(v0) - 1.f;
            v1 = v1 > 0.f ? v1 : __expf(v1) - 1.f;
            if (OUT) {
                v0 = v0 > 0.f ? v0 : __expf(v0) - 1.f;
                v1 = v1 > 0.f ? v1 : __expf(v1) - 1.f;
            }
            if (FINAL) {
                size_t base = ((size_t)b * Nn + i0 + w * 16 + r) * Ff + dstcol;
                dst[base + am] = v0;
                dst[base + 16 + am] = v1;
            } else {
                Tw[r * TSTR + am] = (f16)v0;
                Tw[r * TSTR + 16 + am] = (f16)v1;
            }
        }
        if (!FINAL) {
            // in-wave read-back in A-frag order (no barrier: same wave's data)
            f16x8 o = *(const f16x8*)&Tw[am * TSTR + aq * 8];
            int mt = (b * Nn + i0 + w * 16) >> 4;  // GLOBAL row tile
            int c = dstcol >> 5;
            *(f16x8*)&AfOut[(size_t)(mt * 8 + c) * 512 + lane * 8] = o;
        }
    }
}

// ---------------------------------------------------------------------------
extern "C" void kernel_launch(void* const* d_in, const int* in_sizes, int n_in,
                              void* d_out, int out_size, void* d_ws, size_t ws_size,
                              hipStream_t stream) {
    const float* x = (const float*)d_in[0];
    const int* adj = (const int*)d_in[1];
    const float* W_heads = (const float*)d_in[2];
    const float* a_heads = (const float*)d_in[3];
    const float* W_out = (const float*)d_in[4];
    const float* a_out = (const float*)d_in[5];
    float* out = (float*)d_out;

    float* ws = (float*)d_ws;
    const size_t M = (size_t)Bc * Nn * Ff;        // 1,048,576
    f16* Af_a = (f16*)ws;                         // M f16
    f16* Af_b = (f16*)(ws + M / 2);               // M f16
    f16* WhFrag = (f16*)(ws + M);                 // M f16
    u32* maskT = (u32*)(ws + 3 * M / 2);          // 1 MB
    f16* WTF = (f16*)(ws + 3 * M / 2 + M / 4);    // 6*F*F f16 = 196608 floats
    float* sbuf = ws + 3 * M / 2 + M / 4 + 196608;
    const size_t SH = (size_t)Bc * Hh * Nn;       // 32768
    const size_t SO = (size_t)Bc * Nn;            // 4096
    const size_t SL = 2 * SH + 2 * SO;

    prep_kernel<<<1024, 256, 0, stream>>>(adj, x, W_heads, W_out,
                                          maskT, Af_a, WTF, sbuf);

    for (int l = 0; l < 3; ++l) {
        float* s1h = sbuf + l * SL;
        float* s2h = s1h + SH;
        float* s1o = s2h + SH;
        float* s2o = s1o + SO;

        // ---- head GAT: G=8, O=32 ----
        gemm_wave<<<dim3((Bc * Nn) / 64, Ff / 16), 256, 0, stream>>>(
            Af_a, WTF + (size_t)(2 * l) * Ff * Ff,
            a_heads + (size_t)l * Hh * 2 * Oo, WhFrag, s1h, s2h, Hh, Oo, 5);
        attn_kernel<false, false><<<dim3(Nn / 32, 1, Bc * Hh), 256, 0, stream>>>(
            WhFrag, s1h, s2h, maskT, nullptr, Af_b);

        // ---- out GAT: G=1, O=F=256 ----
        gemm_wave<<<dim3((Bc * Nn) / 64, Ff / 16), 256, 0, stream>>>(
            Af_b, WTF + (size_t)(2 * l + 1) * Ff * Ff,
            a_out + (size_t)l * 2 * Ff, WhFrag, s1o, s2o, 1, Ff, 8);
        if (l == 2) {
            attn_kernel<true, true><<<dim3(Nn / 32, Ff / 32, Bc), 256, 0, stream>>>(
                WhFrag, s1o, s2o, maskT, out, nullptr);
        } else {
            attn_kernel<true, false><<<dim3(Nn / 32, Ff / 32, Bc), 256, 0, stream>>>(
                WhFrag, s1o, s2o, maskT, nullptr, Af_a);
        }
    }
}

// Round 15
// 268.307 us; speedup vs baseline: 2.8421x; 1.0798x over previous
//
#include <hip/hip_runtime.h>
#include <math.h>

#if __has_builtin(__builtin_amdgcn_exp2f)
#define EXP2(x) __builtin_amdgcn_exp2f(x)
#else
#define EXP2(x) exp2f(x)
#endif

#define ALPHA_LRELU 0.2f
#define LOG2E 1.4426950408889634f
#define ESHIFT 6.0f
#define BIGM 1024.0f  // bit=0 -> exp2 arg < -1000 -> p = 0

constexpr int Bc = 2, Nn = 2048, Ff = 256, Hh = 8, Oo = 32;

typedef _Float16 f16;
typedef f16 f16x8 __attribute__((ext_vector_type(8)));
typedef f16 f16x4 __attribute__((ext_vector_type(4)));
typedef float f32x4 __attribute__((ext_vector_type(4)));
typedef unsigned long long u64;
typedef unsigned u32;

// ---------------------------------------------------------------------------
// Fused prep (R14, unchanged): zero s-bufs; B<768: adj->maskT; 768..895:
// apack x; 896..1023: weights -> B-frag WTF.
// ---------------------------------------------------------------------------
__global__ __launch_bounds__(256) void prep_kernel(
    const int* __restrict__ adj, const float* __restrict__ x,
    const float* __restrict__ W_heads, const float* __restrict__ W_out,
    u32* __restrict__ maskT, f16* __restrict__ Af, f16* __restrict__ WTF,
    float* __restrict__ sbuf) {
    const int B = blockIdx.x;
    const int t = threadIdx.x;
    int g = B * 256 + t;
    if (g < 221184) sbuf[g] = 0.f;  // 3 * (2*SH + 2*SO)

    if (B < 768) {
        for (int idx = g; idx < Bc * Nn * Nn; idx += 768 * 256) {
            u64 bl = __ballot(adj[idx] != 0);
            int lane = t & 63;
            int i = (idx >> 11) & 2047;
            int b = idx >> 22;
            int c32 = ((idx & 2047) & ~63) >> 5;
            if (lane == 0)
                maskT[((size_t)b * 64 + c32) * 2048 + i] = (u32)bl;
            else if (lane == 1)
                maskT[((size_t)b * 64 + c32 + 1) * 2048 + i] = (u32)(bl >> 32);
        }
    } else if (B < 896) {
        int w = t >> 6, lane = t & 63;
        int am = lane & 15, aq = lane >> 4;
#pragma unroll
        for (int it = 0; it < 4; ++it) {
            int slot = (B - 768) * 4 + w + it * 512;
            int mt = slot >> 3, c = slot & 7;
            const float* ap = x + ((size_t)mt * 16 + am) * Ff + c * 32 + aq * 8;
            f32x4 v0 = *(const f32x4*)ap;
            f32x4 v1 = *(const f32x4*)(ap + 4);
            f16x8 o;
#pragma unroll
            for (int i = 0; i < 4; ++i) { o[i] = (f16)v0[i]; o[4 + i] = (f16)v1[i]; }
            *(f16x8*)&Af[(size_t)slot * 512 + lane * 8] = o;
        }
    } else {
#pragma unroll
        for (int it = 0; it < 3; ++it) {
            int unit = (B - 896) * 3 + it;  // 0..383
            int y = unit >> 6, bx = unit & 63;
            int ll = y >> 1, st = y & 1;
            int col = bx * 4 + (t >> 6);
            int k0 = (t & 63) * 4;
            const float* src;
            int stride;
            if (st == 0) {
                src = W_heads + (((size_t)ll * Hh + (col >> 5)) * Ff) * Oo + (col & 31);
                stride = Oo;
            } else {
                src = W_out + (size_t)ll * Ff * Ff + col;
                stride = Ff;
            }
            f16x4 v;
#pragma unroll
            for (int i = 0; i < 4; ++i) v[i] = (f16)src[(size_t)(k0 + i) * stride];
            int cg = col >> 4, am = col & 15;
            int c = k0 >> 5, aq = (k0 >> 3) & 3, i0 = k0 & 7;
            *(f16x4*)&WTF[(((size_t)y * 16 + cg) * 8 + c) * 512 +
                          (aq * 16 + am) * 8 + i0] = v;
        }
    }
}

// ---------------------------------------------------------------------------
// Frag GEMM, FULL-PRELOAD: all 8 A-frag + 8 B-frag loads issued up front
// (64 VGPRs of operands), then 8 MFMAs drain -> one latency ramp per wave
// instead of eight. Epilogue unchanged (WhFrag + s1/s2 atomics).
// ---------------------------------------------------------------------------
__global__ __launch_bounds__(256) void gemm_wave(
    const f16* __restrict__ Af, const f16* __restrict__ WTF,
    const float* __restrict__ pa, f16* __restrict__ WhFrag,
    float* __restrict__ s1, float* __restrict__ s2,
    int G, int Ofull, int oshift) {
    int t = threadIdx.x;
    int w = t >> 6, lane = t & 63;
    int am = lane & 15, aq = lane >> 4;
    int mt = blockIdx.x * 4 + w;
    int colb = blockIdx.y * 16;

    const f16* ap = Af + (size_t)(mt * 8) * 512 + lane * 8;
    const f16* bp = WTF + (size_t)((colb >> 4) * 8) * 512 + lane * 8;

    f16x8 av[8], bv[8];
#pragma unroll
    for (int c = 0; c < 8; ++c) {
        av[c] = *(const f16x8*)(ap + c * 512);
        bv[c] = *(const f16x8*)(bp + c * 512);
    }
    f32x4 acc = {0.f, 0.f, 0.f, 0.f};
#pragma unroll
    for (int c = 0; c < 8; ++c)
        acc = __builtin_amdgcn_mfma_f32_16x16x32_f16(av[c], bv[c], acc, 0, 0, 0);

    int m0 = mt * 16;
    int b = m0 >> 11;
    int nn0 = (m0 & 2047) + aq * 4;
    int cO = (m0 & 2047) >> 5;
    int aq_p = ((mt & 1) << 1) | (aq >> 1);
    int i0p = (aq & 1) << 2;
    int g = colb >> oshift;
    size_t bg = (size_t)b * G + g;
    int cg = (colb & (Ofull - 1)) >> 4;

    f16x4 c4;
#pragma unroll
    for (int e = 0; e < 4; ++e) c4[e] = (f16)acc[e];
    *(f16x4*)&WhFrag[(((bg * (Ofull >> 4) + cg) * 64 + cO) * 512) +
                     (aq_p * 16 + am) * 8 + i0p] = c4;

    int o0 = (colb & (Ofull - 1)) + am;
    const float* a1p = pa + 2 * (size_t)g * Ofull;
    float a10 = a1p[o0];
    float a20 = a1p[Ofull + o0];
#pragma unroll
    for (int e = 0; e < 4; ++e) {
        float p1 = acc[e] * a10;
        float p2 = acc[e] * a20;
#pragma unroll
        for (int s = 1; s < 16; s <<= 1) {
            p1 += __shfl_xor(p1, s);
            p2 += __shfl_xor(p2, s);
        }
        if (am == 0) {
            size_t sidx = bg * Nn + nn0 + e;
            atomicAdd(&s1[sidx], p1);
            atomicAdd(&s2[sidx], p2);
        }
    }
}

// ---------------------------------------------------------------------------
// Attention: wave = 2 row-tiles (32 rows) x CGW*16 cols, j-split x4.
// CGW=2 head (full head, no redundancy); CGW=4 out (e-redundancy x8 -> x4).
// B-frags serve both row tiles (L1-intensity win, R14). Prefetch-2.
// End: one barrier, 4-way LDS combine, waves 0/1 run the two tile epilogues.
// ---------------------------------------------------------------------------
template <int CGW, bool OUT, bool FINAL>
__global__ __launch_bounds__(256) void attn_kernel(
    const f16* __restrict__ WhFrag, const float* __restrict__ s1,
    const float* __restrict__ s2, const u32* __restrict__ maskT,
    float* __restrict__ dst, f16* __restrict__ AfOut) {
    constexpr float C0 = -ESHIFT * LOG2E - BIGM;
    constexpr int NCG = OUT ? 16 : 2;
    constexpr int TSTR = 72;  // covers up to 64 cols + pad (16B-aligned rows)
    __shared__ float Ls[4][2][64];
    __shared__ float As[4][64][2 * CGW * 4];
    __shared__ f16 T[2][16 * TSTR];

    int t = threadIdx.x;
    int w = t >> 6, lane = t & 63;
    int am = lane & 15, aq = lane >> 4;
    int i0 = blockIdx.x * 32;
    int bz = blockIdx.z;
    int b = OUT ? bz : (bz >> 3);
    int cg0 = OUT ? blockIdx.y * CGW : 0;
    int dstcol = OUT ? cg0 * 16 : (bz & 7) * Oo;

    const f16* bp[CGW];
#pragma unroll
    for (int i = 0; i < CGW; ++i)
        bp[i] = WhFrag + ((size_t)bz * NCG + cg0 + i) * 64 * 512 + lane * 8;
    const float* s2p = s2 + (size_t)bz * Nn + aq * 8;
    float s1v0 = s1[(size_t)bz * Nn + i0 + am];
    float s1v1 = s1[(size_t)bz * Nn + i0 + 16 + am];
    const u32* mtp0 = maskT + (size_t)b * 64 * 2048 + i0 + am;
    const u32* mtp1 = mtp0 + 16;

    f32x4 acc[2][CGW] = {};
    float lacc0 = 0.f, lacc1 = 0.f;

    int cbeg = w * 16, cend = cbeg + 16;  // this wave's j-slice (16 chunks)

    f16x8 xb[CGW], yb[CGW];
    f32x4 xv0, xv1, yv0, yv1;
    u32 xm0, xm1, ym0, ym1;
    auto ld = [&](int c, f16x8 (&bb)[CGW], f32x4& v0, f32x4& v1,
                  u32& m0, u32& m1) {
#pragma unroll
        for (int i = 0; i < CGW; ++i) bb[i] = *(const f16x8*)(bp[i] + c * 512);
        v0 = *(const f32x4*)(s2p + c * 32);
        v1 = *(const f32x4*)(s2p + c * 32 + 4);
        m0 = mtp0[c * 2048];
        m1 = mtp1[c * 2048];
    };
    auto comp = [&](f16x8 (&bb)[CGW], f32x4 v0, f32x4 v1, u32 m0, u32 m1) {
        u32 bits0 = (m0 >> (aq * 8)) & 0xffu;
        u32 bits1 = (m1 >> (aq * 8)) & 0xffu;
        f16x8 af0, af1;
#pragma unroll
        for (int k = 0; k < 8; ++k) {
            float sv = (k < 4 ? v0[k] : v1[k - 4]);
            float x0 = s1v0 + sv;
            float x1 = s1v1 + sv;
            float lr0 = fmaxf(x0, ALPHA_LRELU * x0);
            float lr1 = fmaxf(x1, ALPHA_LRELU * x1);
            float bf0 = (float)((bits0 >> k) & 1u);
            float bf1 = (float)((bits1 >> k) & 1u);
            float p0 = EXP2(fmaf(bf0, BIGM, fmaf(lr0, LOG2E, C0)));
            float p1 = EXP2(fmaf(bf1, BIGM, fmaf(lr1, LOG2E, C0)));
            lacc0 += p0;
            lacc1 += p1;
            af0[k] = (f16)p0;
            af1[k] = (f16)p1;
        }
#pragma unroll
        for (int i = 0; i < CGW; ++i) {
            acc[0][i] = __builtin_amdgcn_mfma_f32_16x16x32_f16(af0, bb[i], acc[0][i], 0, 0, 0);
            acc[1][i] = __builtin_amdgcn_mfma_f32_16x16x32_f16(af1, bb[i], acc[1][i], 0, 0, 0);
        }
    };

    ld(cbeg, xb, xv0, xv1, xm0, xm1);
    ld(cbeg + 1, yb, yv0, yv1, ym0, ym1);
    for (int c = cbeg; c < cend; c += 2) {
        comp(xb, xv0, xv1, xm0, xm1);
        ld(c + 2 < cend ? c + 2 : cbeg, xb, xv0, xv1, xm0, xm1);
        comp(yb, yv0, yv1, ym0, ym1);
        ld(c + 3 < cend ? c + 3 : cbeg, yb, yv0, yv1, ym0, ym1);
    }

    // intra-wave l: sum over aq groups -> lane holds l_slice[am] per tile
    lacc0 += __shfl_xor(lacc0, 16);
    lacc0 += __shfl_xor(lacc0, 32);
    lacc1 += __shfl_xor(lacc1, 16);
    lacc1 += __shfl_xor(lacc1, 32);

    Ls[w][0][lane] = lacc0;
    Ls[w][1][lane] = lacc1;
#pragma unroll
    for (int tt = 0; tt < 2; ++tt)
#pragma unroll
        for (int i = 0; i < CGW; ++i)
#pragma unroll
            for (int e = 0; e < 4; ++e)
                As[w][lane][tt * CGW * 4 + i * 4 + e] = acc[tt][i][e];
    __syncthreads();

    if (w < 2) {  // wave w finishes row tile w
        float lt = Ls[0][w][lane] + Ls[1][w][lane] + Ls[2][w][lane] + Ls[3][w][lane];
        f16* Tw = T[w];
#pragma unroll
        for (int i = 0; i < CGW; ++i) {
            f32x4 a;
#pragma unroll
            for (int e = 0; e < 4; ++e)
                a[e] = As[0][lane][w * CGW * 4 + i * 4 + e] +
                       As[1][lane][w * CGW * 4 + i * 4 + e] +
                       As[2][lane][w * CGW * 4 + i * 4 + e] +
                       As[3][lane][w * CGW * 4 + i * 4 + e];
#pragma unroll
            for (int e = 0; e < 4; ++e) {
                int r = aq * 4 + e;             // C/D: col=am, row=aq*4+e
                float li = __shfl(lt, r);       // lane r holds l[row r]
                float v = a[e] / li;
                v = v > 0.f ? v : __expf(v) - 1.f;
                if (OUT) v = v > 0.f ? v : __expf(v) - 1.f;
                if (FINAL) {
                    dst[((size_t)b * Nn + i0 + w * 16 + r) * Ff + dstcol +
                        i * 16 + am] = v;
                } else {
                    Tw[r * TSTR + i * 16 + am] = (f16)v;
                }
            }
        }
        if (!FINAL) {
            // in-wave read-back in A-frag order (no barrier: same wave's data)
            int mt = (b * Nn + i0 + w * 16) >> 4;  // GLOBAL row tile
#pragma unroll
            for (int s = 0; s < CGW / 2; ++s) {
                f16x8 o = *(const f16x8*)&Tw[am * TSTR + s * 32 + aq * 8];
                int c = (dstcol >> 5) + s;
                *(f16x8*)&AfOut[(size_t)(mt * 8 + c) * 512 + lane * 8] = o;
            }
        }
    }
}

// ---------------------------------------------------------------------------
extern "C" void kernel_launch(void* const* d_in, const int* in_sizes, int n_in,
                              void* d_out, int out_size, void* d_ws, size_t ws_size,
                              hipStream_t stream) {
    const float* x = (const float*)d_in[0];
    const int* adj = (const int*)d_in[1];
    const float* W_heads = (const float*)d_in[2];
    const float* a_heads = (const float*)d_in[3];
    const float* W_out = (const float*)d_in[4];
    const float* a_out = (const float*)d_in[5];
    float* out = (float*)d_out;

    float* ws = (float*)d_ws;
    const size_t M = (size_t)Bc * Nn * Ff;        // 1,048,576
    f16* Af_a = (f16*)ws;                         // M f16
    f16* Af_b = (f16*)(ws + M / 2);               // M f16
    f16* WhFrag = (f16*)(ws + M);                 // M f16
    u32* maskT = (u32*)(ws + 3 * M / 2);          // 1 MB
    f16* WTF = (f16*)(ws + 3 * M / 2 + M / 4);    // 6*F*F f16 = 196608 floats
    float* sbuf = ws + 3 * M / 2 + M / 4 + 196608;
    const size_t SH = (size_t)Bc * Hh * Nn;       // 32768
    const size_t SO = (size_t)Bc * Nn;            // 4096
    const size_t SL = 2 * SH + 2 * SO;

    prep_kernel<<<1024, 256, 0, stream>>>(adj, x, W_heads, W_out,
                                          maskT, Af_a, WTF, sbuf);

    for (int l = 0; l < 3; ++l) {
        float* s1h = sbuf + l * SL;
        float* s2h = s1h + SH;
        float* s1o = s2h + SH;
        float* s2o = s1o + SO;

        // ---- head GAT: G=8, O=32 ----
        gemm_wave<<<dim3((Bc * Nn) / 64, Ff / 16), 256, 0, stream>>>(
            Af_a, WTF + (size_t)(2 * l) * Ff * Ff,
            a_heads + (size_t)l * Hh * 2 * Oo, WhFrag, s1h, s2h, Hh, Oo, 5);
        attn_kernel<2, false, false><<<dim3(Nn / 32, 1, Bc * Hh), 256, 0, stream>>>(
            WhFrag, s1h, s2h, maskT, nullptr, Af_b);

        // ---- out GAT: G=1, O=F=256 ----
        gemm_wave<<<dim3((Bc * Nn) / 64, Ff / 16), 256, 0, stream>>>(
            Af_b, WTF + (size_t)(2 * l + 1) * Ff * Ff,
            a_out + (size_t)l * 2 * Ff, WhFrag, s1o, s2o, 1, Ff, 8);
        if (l == 2) {
            attn_kernel<4, true, true><<<dim3(Nn / 32, Ff / 64, Bc), 256, 0, stream>>>(
                WhFrag, s1o, s2o, maskT, out, nullptr);
        } else {
            attn_kernel<4, true, false><<<dim3(Nn / 32, Ff / 64, Bc), 256, 0, stream>>>(
                WhFrag, s1o, s2o, maskT, nullptr, Af_a);
        }
    }
}

// Round 16
// 267.197 us; speedup vs baseline: 2.8539x; 1.0042x over previous
//
#include <hip/hip_runtime.h>
#include <math.h>

#if __has_builtin(__builtin_amdgcn_exp2f)
#define EXP2(x) __builtin_amdgcn_exp2f(x)
#else
#define EXP2(x) exp2f(x)
#endif

#define ALPHA_LRELU 0.2f
#define LOG2E 1.4426950408889634f
#define ESHIFT 6.0f
#define BIGM 1024.0f  // bit=0 -> exp2 arg < -1000 -> p = 0

constexpr int Bc = 2, Nn = 2048, Ff = 256, Hh = 8, Oo = 32;

typedef _Float16 f16;
typedef f16 f16x8 __attribute__((ext_vector_type(8)));
typedef f16 f16x4 __attribute__((ext_vector_type(4)));
typedef float f32x4 __attribute__((ext_vector_type(4)));
typedef unsigned long long u64;
typedef unsigned u32;

// ---------------------------------------------------------------------------
// Fused prep (R14, unchanged): zero s-bufs; B<768: adj->maskT; 768..895:
// apack x; 896..1023: weights -> B-frag WTF.
// ---------------------------------------------------------------------------
__global__ __launch_bounds__(256) void prep_kernel(
    const int* __restrict__ adj, const float* __restrict__ x,
    const float* __restrict__ W_heads, const float* __restrict__ W_out,
    u32* __restrict__ maskT, f16* __restrict__ Af, f16* __restrict__ WTF,
    float* __restrict__ sbuf) {
    const int B = blockIdx.x;
    const int t = threadIdx.x;
    int g = B * 256 + t;
    if (g < 221184) sbuf[g] = 0.f;  // 3 * (2*SH + 2*SO)

    if (B < 768) {
        for (int idx = g; idx < Bc * Nn * Nn; idx += 768 * 256) {
            u64 bl = __ballot(adj[idx] != 0);
            int lane = t & 63;
            int i = (idx >> 11) & 2047;
            int b = idx >> 22;
            int c32 = ((idx & 2047) & ~63) >> 5;
            if (lane == 0)
                maskT[((size_t)b * 64 + c32) * 2048 + i] = (u32)bl;
            else if (lane == 1)
                maskT[((size_t)b * 64 + c32 + 1) * 2048 + i] = (u32)(bl >> 32);
        }
    } else if (B < 896) {
        int w = t >> 6, lane = t & 63;
        int am = lane & 15, aq = lane >> 4;
#pragma unroll
        for (int it = 0; it < 4; ++it) {
            int slot = (B - 768) * 4 + w + it * 512;
            int mt = slot >> 3, c = slot & 7;
            const float* ap = x + ((size_t)mt * 16 + am) * Ff + c * 32 + aq * 8;
            f32x4 v0 = *(const f32x4*)ap;
            f32x4 v1 = *(const f32x4*)(ap + 4);
            f16x8 o;
#pragma unroll
            for (int i = 0; i < 4; ++i) { o[i] = (f16)v0[i]; o[4 + i] = (f16)v1[i]; }
            *(f16x8*)&Af[(size_t)slot * 512 + lane * 8] = o;
        }
    } else {
#pragma unroll
        for (int it = 0; it < 3; ++it) {
            int unit = (B - 896) * 3 + it;  // 0..383
            int y = unit >> 6, bx = unit & 63;
            int ll = y >> 1, st = y & 1;
            int col = bx * 4 + (t >> 6);
            int k0 = (t & 63) * 4;
            const float* src;
            int stride;
            if (st == 0) {
                src = W_heads + (((size_t)ll * Hh + (col >> 5)) * Ff) * Oo + (col & 31);
                stride = Oo;
            } else {
                src = W_out + (size_t)ll * Ff * Ff + col;
                stride = Ff;
            }
            f16x4 v;
#pragma unroll
            for (int i = 0; i < 4; ++i) v[i] = (f16)src[(size_t)(k0 + i) * stride];
            int cg = col >> 4, am = col & 15;
            int c = k0 >> 5, aq = (k0 >> 3) & 3, i0 = k0 & 7;
            *(f16x4*)&WTF[(((size_t)y * 16 + cg) * 8 + c) * 512 +
                          (aq * 16 + am) * 8 + i0] = v;
        }
    }
}

// ---------------------------------------------------------------------------
// Frag GEMM: wave = 16 rows x 32 cols (2 cg), FULL-PRELOAD (8 A + 16 B
// frags). A-frags serve 2 col-groups -> A L2 traffic halved vs R15.
// Grid (64, 8) = 512 blocks. Epilogue: 2 WhFrag writes + s1/s2 atomics.
// ---------------------------------------------------------------------------
__global__ __launch_bounds__(256) void gemm_wave(
    const f16* __restrict__ Af, const f16* __restrict__ WTF,
    const float* __restrict__ pa, f16* __restrict__ WhFrag,
    float* __restrict__ s1, float* __restrict__ s2,
    int G, int Ofull, int oshift) {
    int t = threadIdx.x;
    int w = t >> 6, lane = t & 63;
    int am = lane & 15, aq = lane >> 4;
    int mt = blockIdx.x * 4 + w;
    int colb = blockIdx.y * 32;

    const f16* ap = Af + (size_t)(mt * 8) * 512 + lane * 8;
    const f16* bp0 = WTF + (size_t)((colb >> 4) * 8) * 512 + lane * 8;
    const f16* bp1 = bp0 + 8 * 512;

    f16x8 av[8], bv0[8], bv1[8];
#pragma unroll
    for (int c = 0; c < 8; ++c) {
        av[c] = *(const f16x8*)(ap + c * 512);
        bv0[c] = *(const f16x8*)(bp0 + c * 512);
        bv1[c] = *(const f16x8*)(bp1 + c * 512);
    }
    f32x4 acc0 = {0.f, 0.f, 0.f, 0.f}, acc1 = acc0;
#pragma unroll
    for (int c = 0; c < 8; ++c) {
        acc0 = __builtin_amdgcn_mfma_f32_16x16x32_f16(av[c], bv0[c], acc0, 0, 0, 0);
        acc1 = __builtin_amdgcn_mfma_f32_16x16x32_f16(av[c], bv1[c], acc1, 0, 0, 0);
    }

    int m0 = mt * 16;
    int b = m0 >> 11;
    int nn0 = (m0 & 2047) + aq * 4;
    int cO = (m0 & 2047) >> 5;
    int aq_p = ((mt & 1) << 1) | (aq >> 1);
    int i0p = (aq & 1) << 2;
    int g = colb >> oshift;  // 32 cols within one g (head: colb mult of 32)
    size_t bg = (size_t)b * G + g;
    int cg = (colb & (Ofull - 1)) >> 4;

    f16x4 c40, c41;
#pragma unroll
    for (int e = 0; e < 4; ++e) { c40[e] = (f16)acc0[e]; c41[e] = (f16)acc1[e]; }
    *(f16x4*)&WhFrag[(((bg * (Ofull >> 4) + cg) * 64 + cO) * 512) +
                     (aq_p * 16 + am) * 8 + i0p] = c40;
    *(f16x4*)&WhFrag[(((bg * (Ofull >> 4) + cg + 1) * 64 + cO) * 512) +
                     (aq_p * 16 + am) * 8 + i0p] = c41;

    int o0 = (colb & (Ofull - 1)) + am;
    const float* a1p = pa + 2 * (size_t)g * Ofull;
    float a10 = a1p[o0], a11 = a1p[o0 + 16];
    float a20 = a1p[Ofull + o0], a21 = a1p[Ofull + o0 + 16];
#pragma unroll
    for (int e = 0; e < 4; ++e) {
        float p1 = acc0[e] * a10 + acc1[e] * a11;
        float p2 = acc0[e] * a20 + acc1[e] * a21;
#pragma unroll
        for (int s = 1; s < 16; s <<= 1) {
            p1 += __shfl_xor(p1, s);
            p2 += __shfl_xor(p2, s);
        }
        if (am == 0) {
            size_t sidx = bg * Nn + nn0 + e;
            atomicAdd(&s1[sidx], p1);
            atomicAdd(&s2[sidx], p2);
        }
    }
}

// ---------------------------------------------------------------------------
// Attention: NW waves = (NW/4 col-halves) x (4 j-slices); each wave =
// 2 row-tiles (32 rows) x CGW*16 cols, prefetch-2, e-in-registers.
// Head: NW=4 (256 thr), CGW=2, grid (64,1,16).
// Out:  NW=8 (512 thr), CGW=4, grid (64,2,2) -> block covers 128 cols,
//       e-redundancy x2 (was x4 in R15).
// End: one barrier, 4-way j-slice LDS combine per col-half, waves with
// (w&3)<2 run the tile epilogues (verbatim R12 numerics + Af writeback).
// ---------------------------------------------------------------------------
template <int CGW, int NW, bool OUT, bool FINAL>
__global__ __launch_bounds__(NW * 64) void attn_kernel(
    const f16* __restrict__ WhFrag, const float* __restrict__ s1,
    const float* __restrict__ s2, const u32* __restrict__ maskT,
    float* __restrict__ dst, f16* __restrict__ AfOut) {
    constexpr float C0 = -ESHIFT * LOG2E - BIGM;
    constexpr int NCG = OUT ? 16 : 2;
    constexpr int COLS = (NW / 4) * CGW * 16;  // block col coverage
    constexpr int TSTR = COLS + 8;             // f16 LDS row stride, 16B-aligned
    __shared__ float Ls[NW][2][64];
    __shared__ float As[NW][64][2 * CGW * 4];
    __shared__ f16 T[2][16 * TSTR];

    int t = threadIdx.x;
    int w = t >> 6, lane = t & 63;
    int am = lane & 15, aq = lane >> 4;
    int ch = w >> 2;   // col-half
    int js = w & 3;    // j-slice
    int i0 = blockIdx.x * 32;
    int bz = blockIdx.z;
    int b = OUT ? bz : (bz >> 3);
    int cg0 = OUT ? blockIdx.y * ((NW / 4) * CGW) + ch * CGW : 0;
    int dstcol = OUT ? cg0 * 16 : (bz & 7) * Oo;

    const f16* bp[CGW];
#pragma unroll
    for (int i = 0; i < CGW; ++i)
        bp[i] = WhFrag + ((size_t)bz * NCG + cg0 + i) * 64 * 512 + lane * 8;
    const float* s2p = s2 + (size_t)bz * Nn + aq * 8;
    float s1v0 = s1[(size_t)bz * Nn + i0 + am];
    float s1v1 = s1[(size_t)bz * Nn + i0 + 16 + am];
    const u32* mtp0 = maskT + (size_t)b * 64 * 2048 + i0 + am;
    const u32* mtp1 = mtp0 + 16;

    f32x4 acc[2][CGW] = {};
    float lacc0 = 0.f, lacc1 = 0.f;

    int cbeg = js * 16, cend = cbeg + 16;  // this wave's j-slice (16 chunks)

    f16x8 xb[CGW], yb[CGW];
    f32x4 xv0, xv1, yv0, yv1;
    u32 xm0, xm1, ym0, ym1;
    auto ld = [&](int c, f16x8 (&bb)[CGW], f32x4& v0, f32x4& v1,
                  u32& m0, u32& m1) {
#pragma unroll
        for (int i = 0; i < CGW; ++i) bb[i] = *(const f16x8*)(bp[i] + c * 512);
        v0 = *(const f32x4*)(s2p + c * 32);
        v1 = *(const f32x4*)(s2p + c * 32 + 4);
        m0 = mtp0[c * 2048];
        m1 = mtp1[c * 2048];
    };
    auto comp = [&](f16x8 (&bb)[CGW], f32x4 v0, f32x4 v1, u32 m0, u32 m1) {
        u32 bits0 = (m0 >> (aq * 8)) & 0xffu;
        u32 bits1 = (m1 >> (aq * 8)) & 0xffu;
        f16x8 af0, af1;
#pragma unroll
        for (int k = 0; k < 8; ++k) {
            float sv = (k < 4 ? v0[k] : v1[k - 4]);
            float x0 = s1v0 + sv;
            float x1 = s1v1 + sv;
            float lr0 = fmaxf(x0, ALPHA_LRELU * x0);
            float lr1 = fmaxf(x1, ALPHA_LRELU * x1);
            float bf0 = (float)((bits0 >> k) & 1u);
            float bf1 = (float)((bits1 >> k) & 1u);
            float p0 = EXP2(fmaf(bf0, BIGM, fmaf(lr0, LOG2E, C0)));
            float p1 = EXP2(fmaf(bf1, BIGM, fmaf(lr1, LOG2E, C0)));
            lacc0 += p0;
            lacc1 += p1;
            af0[k] = (f16)p0;
            af1[k] = (f16)p1;
        }
#pragma unroll
        for (int i = 0; i < CGW; ++i) {
            acc[0][i] = __builtin_amdgcn_mfma_f32_16x16x32_f16(af0, bb[i], acc[0][i], 0, 0, 0);
            acc[1][i] = __builtin_amdgcn_mfma_f32_16x16x32_f16(af1, bb[i], acc[1][i], 0, 0, 0);
        }
    };

    ld(cbeg, xb, xv0, xv1, xm0, xm1);
    ld(cbeg + 1, yb, yv0, yv1, ym0, ym1);
    for (int c = cbeg; c < cend; c += 2) {
        comp(xb, xv0, xv1, xm0, xm1);
        ld(c + 2 < cend ? c + 2 : cbeg, xb, xv0, xv1, xm0, xm1);
        comp(yb, yv0, yv1, ym0, ym1);
        ld(c + 3 < cend ? c + 3 : cbeg, yb, yv0, yv1, ym0, ym1);
    }

    // intra-wave l: sum over aq groups -> lane holds l_slice[am] per tile
    lacc0 += __shfl_xor(lacc0, 16);
    lacc0 += __shfl_xor(lacc0, 32);
    lacc1 += __shfl_xor(lacc1, 16);
    lacc1 += __shfl_xor(lacc1, 32);

    Ls[w][0][lane] = lacc0;
    Ls[w][1][lane] = lacc1;
#pragma unroll
    for (int tt = 0; tt < 2; ++tt)
#pragma unroll
        for (int i = 0; i < CGW; ++i)
#pragma unroll
            for (int e = 0; e < 4; ++e)
                As[w][lane][tt * CGW * 4 + i * 4 + e] = acc[tt][i][e];
    __syncthreads();

    if ((w & 3) < 2) {  // wave (ch, tt=js) finishes row tile tt for its cols
        int tt = w & 3;
        float lt = Ls[ch * 4 + 0][tt][lane] + Ls[ch * 4 + 1][tt][lane] +
                   Ls[ch * 4 + 2][tt][lane] + Ls[ch * 4 + 3][tt][lane];
        f16* Tw = T[tt];
#pragma unroll
        for (int i = 0; i < CGW; ++i) {
            f32x4 a;
#pragma unroll
            for (int e = 0; e < 4; ++e)
                a[e] = As[ch * 4 + 0][lane][tt * CGW * 4 + i * 4 + e] +
                       As[ch * 4 + 1][lane][tt * CGW * 4 + i * 4 + e] +
                       As[ch * 4 + 2][lane][tt * CGW * 4 + i * 4 + e] +
                       As[ch * 4 + 3][lane][tt * CGW * 4 + i * 4 + e];
#pragma unroll
            for (int e = 0; e < 4; ++e) {
                int r = aq * 4 + e;             // C/D: col=am, row=aq*4+e
                float li = __shfl(lt, r);       // lane r holds l[row r]
                float v = a[e] / li;
                v = v > 0.f ? v : __expf(v) - 1.f;
                if (OUT) v = v > 0.f ? v : __expf(v) - 1.f;
                if (FINAL) {
                    dst[((size_t)b * Nn + i0 + tt * 16 + r) * Ff + dstcol +
                        i * 16 + am] = v;
                } else {
                    Tw[r * TSTR + ch * CGW * 16 + i * 16 + am] = (f16)v;
                }
            }
        }
        if (!FINAL) {
            // in-wave read-back in A-frag order (no barrier: same wave's data)
            int mt = (b * Nn + i0 + tt * 16) >> 4;  // GLOBAL row tile
#pragma unroll
            for (int s = 0; s < CGW / 2; ++s) {
                f16x8 o = *(const f16x8*)&Tw[am * TSTR + ch * CGW * 16 +
                                             s * 32 + aq * 8];
                int c = (dstcol >> 5) + s;
                *(f16x8*)&AfOut[(size_t)(mt * 8 + c) * 512 + lane * 8] = o;
            }
        }
    }
}

// ---------------------------------------------------------------------------
extern "C" void kernel_launch(void* const* d_in, const int* in_sizes, int n_in,
                              void* d_out, int out_size, void* d_ws, size_t ws_size,
                              hipStream_t stream) {
    const float* x = (const float*)d_in[0];
    const int* adj = (const int*)d_in[1];
    const float* W_heads = (const float*)d_in[2];
    const float* a_heads = (const float*)d_in[3];
    const float* W_out = (const float*)d_in[4];
    const float* a_out = (const float*)d_in[5];
    float* out = (float*)d_out;

    float* ws = (float*)d_ws;
    const size_t M = (size_t)Bc * Nn * Ff;        // 1,048,576
    f16* Af_a = (f16*)ws;                         // M f16
    f16* Af_b = (f16*)(ws + M / 2);               // M f16
    f16* WhFrag = (f16*)(ws + M);                 // M f16
    u32* maskT = (u32*)(ws + 3 * M / 2);          // 1 MB
    f16* WTF = (f16*)(ws + 3 * M / 2 + M / 4);    // 6*F*F f16 = 196608 floats
    float* sbuf = ws + 3 * M / 2 + M / 4 + 196608;
    const size_t SH = (size_t)Bc * Hh * Nn;       // 32768
    const size_t SO = (size_t)Bc * Nn;            // 4096
    const size_t SL = 2 * SH + 2 * SO;

    prep_kernel<<<1024, 256, 0, stream>>>(adj, x, W_heads, W_out,
                                          maskT, Af_a, WTF, sbuf);

    for (int l = 0; l < 3; ++l) {
        float* s1h = sbuf + l * SL;
        float* s2h = s1h + SH;
        float* s1o = s2h + SH;
        float* s2o = s1o + SO;

        // ---- head GAT: G=8, O=32 ----
        gemm_wave<<<dim3((Bc * Nn) / 64, Ff / 32), 256, 0, stream>>>(
            Af_a, WTF + (size_t)(2 * l) * Ff * Ff,
            a_heads + (size_t)l * Hh * 2 * Oo, WhFrag, s1h, s2h, Hh, Oo, 5);
        attn_kernel<2, 4, false, false><<<dim3(Nn / 32, 1, Bc * Hh), 256, 0, stream>>>(
            WhFrag, s1h, s2h, maskT, nullptr, Af_b);

        // ---- out GAT: G=1, O=F=256 ----
        gemm_wave<<<dim3((Bc * Nn) / 64, Ff / 32), 256, 0, stream>>>(
            Af_b, WTF + (size_t)(2 * l + 1) * Ff * Ff,
            a_out + (size_t)l * 2 * Ff, WhFrag, s1o, s2o, 1, Ff, 8);
        if (l == 2) {
            attn_kernel<4, 8, true, true><<<dim3(Nn / 32, Ff / 128, Bc), 512, 0, stream>>>(
                WhFrag, s1o, s2o, maskT, out, nullptr);
        } else {
            attn_kernel<4, 8, true, false><<<dim3(Nn / 32, Ff / 128, Bc), 512, 0, stream>>>(
                WhFrag, s1o, s2o, maskT, nullptr, Af_a);
        }
    }
}